// Round 16
// baseline (1004.660 us; speedup 1.0000x reference)
//
#include <hip/hip_runtime.h>
#include <hip/hip_bf16.h>
#include <math.h>

#define HID 128
#define KRBF 9
#define NLAYER 3
#define IPADF 132   // fp32 inter LDS row stride (floats): 528B, 16B-aligned rows

typedef __attribute__((ext_vector_type(8))) short bf16x8;
typedef __attribute__((ext_vector_type(4))) float f32x4;

// fast softplus: abs err ~1e-7 (amplifies to ~2e-3 at output — safe)
__device__ __forceinline__ float sp_(float x){
  return fmaxf(x,0.f) + __logf(1.f + __expf(-fabsf(x)));
}
__device__ __forceinline__ float sigm_(float x){ return 1.f/(1.f+__expf(-x)); }
__device__ __forceinline__ float b2f(short s){
  union{unsigned u; float f;} x; x.u = ((unsigned)(unsigned short)s)<<16; return x.f;
}
__device__ __forceinline__ short f2bs(float x){
  __hip_bfloat16 b = __float2bfloat16(x);
  return *reinterpret_cast<short*>(&b);
}
// triple split fp32 -> bf16 hi+mid+lo (x ~= h+m+l, residual ~6e-8 rel)
__device__ __forceinline__ void split3_8(const float* a, bf16x8& hi, bf16x8& mi, bf16x8& lo){
  #pragma unroll
  for(int j=0;j<8;j++){
    float x = a[j];
    short h = f2bs(x); hi[j]=h;
    float r1 = x - b2f(h);
    short m = f2bs(r1); mi[j]=m;
    lo[j] = f2bs(r1 - b2f(m));
  }
}
__device__ __forceinline__ float wsum64(float v){
  #pragma unroll
  for(int m=1;m<64;m<<=1) v += __shfl_xor(v,m,64);
  return v;
}
__device__ __forceinline__ float wsum16(float v){
  #pragma unroll
  for(int m=1;m<16;m<<=1) v += __shfl_xor(v,m,64);
  return v;
}
__device__ __forceinline__ int lb_(const int* __restrict__ a, int n, int key){
  int lo=0, hi=n;
  while(lo<hi){ int mid=(lo+hi)>>1; if(a[mid]<key) lo=mid+1; else hi=mid; }
  return lo;
}

// ---------------- CSR ----------------
__global__ void count_dst(const int* __restrict__ ei, int* __restrict__ counts, int E){
  int e = blockIdx.x*256+threadIdx.x;
  if(e<E) atomicAdd(&counts[ei[E+e]],1);
}
__global__ void scan1(const int* __restrict__ counts, int* __restrict__ tmp,
                      int* __restrict__ bsums, int N){
  __shared__ int lds[256];
  int t = threadIdx.x; int idx = blockIdx.x*256+t;
  int v = (idx<N)? counts[idx]:0;
  lds[t]=v; __syncthreads();
  for(int off=1;off<256;off<<=1){
    int x = (t>=off)? lds[t-off]:0;
    __syncthreads();
    lds[t]+=x; __syncthreads();
  }
  if(idx<N) tmp[idx]=lds[t];
  if(t==255) bsums[blockIdx.x]=lds[255];
}
__global__ void scan2(const int* __restrict__ bsums, int* __restrict__ boffs, int nb){
  __shared__ int lds[256];
  int t=threadIdx.x;
  int v = (t<nb)? bsums[t]:0;
  lds[t]=v; __syncthreads();
  for(int off=1;off<256;off<<=1){
    int x=(t>=off)?lds[t-off]:0;
    __syncthreads();
    lds[t]+=x; __syncthreads();
  }
  if(t<nb) boffs[t] = lds[t]-v; // exclusive
}
__global__ void finalize_rs(const int* __restrict__ tmp, const int* __restrict__ boffs,
                            int* __restrict__ row_start, int N){
  int idx = blockIdx.x*256+threadIdx.x;
  if(idx<N) row_start[idx+1] = tmp[idx] + boffs[idx>>8];
  if(idx==0) row_start[0]=0;
}
__global__ void csr_scatter(const int* __restrict__ ei, const int* __restrict__ rowst,
                            int* __restrict__ counts2, int* __restrict__ csr, int E){
  int e = blockIdx.x*256+threadIdx.x;
  if(e>=E) return;
  int d = ei[E+e];
  int p = rowst[d] + atomicAdd(&counts2[d],1);
  csr[p] = e;
}
// deterministic segment order: insertion-sort each node's edge ids ascending
__global__ void sort_seg(const int* __restrict__ rowst, int* __restrict__ csr, int N){
  int n = blockIdx.x*256+threadIdx.x;
  if(n>=N) return;
  int lo=rowst[n], hi=rowst[n+1];
  for(int i=lo+1;i<hi;i++){
    int v=csr[i]; int j=i-1;
    while(j>=lo && csr[j]>v){ csr[j+1]=csr[j]; j--; }
    csr[j+1]=v;
  }
}
__global__ void edge_feat(const float* __restrict__ pos, const float* __restrict__ ew,
                          const int* __restrict__ ei, const int* __restrict__ csr,
                          float* __restrict__ efs, int* __restrict__ esrc, int E){
  int p = blockIdx.x*256 + threadIdx.x;
  if(p>=E) return;
  int e = csr[p];
  int s = ei[e], d = ei[E+e];
  float dx = pos[d*3+0]-pos[s*3+0];
  float dy = pos[d*3+1]-pos[s*3+1];
  float dz = pos[d*3+2]-pos[s*3+2];
  float D = sqrtf(dx*dx+dy*dy+dz*dz);
  float x = D*0.1f;
  float cut = 0.f;
  if(x < 1.f){ float x3=x*x*x, x4=x3*x, x5=x4*x; cut = 1.f - 6.f*x5 + 15.f*x4 - 10.f*x3; }
  float ed = expf(-D);
  const double e10 = 4.5399929762484854e-05; // exp(-10)
  const float step  = (float)((e10 - 1.0)/8.0);
  const float width = (float)((4.5/(1.0-e10))*(4.5/(1.0-e10)));
  float r12[12];
  #pragma unroll
  for(int k=0;k<KRBF;k++){
    float c = 1.0f + k*step;
    float dd = ed - c;
    r12[k] = cut*expf(-width*dd*dd);
  }
  r12[9] = ew[e]; r12[10]=0.f; r12[11]=0.f;
  float* o = efs + (size_t)p*12;
  *(float4*)&o[0] = *(float4*)&r12[0];
  *(float4*)&o[4] = *(float4*)&r12[4];
  *(float4*)&o[8] = *(float4*)&r12[8];
  esrc[p] = s;
}

// ---------------- weight packing: fragment-flat, TRIPLE-split bf16 planes ----------------
// planes at [0,T), [T,2T), [2T,3T)
__global__ void pack_w(const float* __restrict__ Wq, const float* __restrict__ Wk,
                       const float* __restrict__ Wv, const float* __restrict__ Wsk,
                       const float* __restrict__ bq, const float* __restrict__ bk,
                       const float* __restrict__ bv, const float* __restrict__ bsk,
                       const float* __restrict__ We,
                       const float* __restrict__ W1, const float* __restrict__ W2,
                       const float* __restrict__ W3,
                       __hip_bfloat16* __restrict__ Wqkvs, float* __restrict__ bqkvs,
                       __hip_bfloat16* __restrict__ Wffn){
  int idx = blockIdx.x*256 + threadIdx.x;
  const int QT = NLAYER*5*16384;
  const int FT = NLAYER*3*16384;
  const int BT = NLAYER*640;
  if(idx < QT){
    int l = idx / (5*16384);
    int rem = idx - l*(5*16384);
    int cb = rem >> 14;
    int t = rem & 16383;
    int j = t&7; int lane = (t>>3)&63; int blk = t>>9;
    int kc = blk>>3, nj = blk&7, ql = lane>>4, il = lane&15;
    int k = kc*32 + ql*8 + j;
    int gcol = cb*128 + il*8 + nj;
    float v = 0.f;
    if(gcol < 512){
      const float* src = (gcol<128)?Wq:((gcol<256)?Wk:((gcol<384)?Wv:Wsk));
      v = src[(size_t)l*16384 + k*128 + (gcol&127)];
    } else if(gcol < 552){
      int jj = gcol-512; int h=jj/10; int r=jj-10*h;
      const float* wq = Wq + (size_t)l*16384 + k*128;
      const float* we = We + (size_t)l*1280 + r*128;
      float acc=0.f;
      #pragma unroll 8
      for(int c=32*h;c<32*h+32;c++) acc = fmaf(wq[c], we[c], acc);
      v = acc;
    }
    short hi = f2bs(v);
    float r1 = v - b2f(hi);
    short mi = f2bs(r1);
    short lo = f2bs(r1 - b2f(mi));
    Wqkvs[idx]        = *reinterpret_cast<__hip_bfloat16*>(&hi);
    Wqkvs[QT + idx]   = *reinterpret_cast<__hip_bfloat16*>(&mi);
    Wqkvs[2*QT + idx] = *reinterpret_cast<__hip_bfloat16*>(&lo);
  } else if(idx < QT+FT){
    int r0 = idx - QT;
    int l = r0 / (3*16384);
    int rem = r0 - l*(3*16384);
    int f = rem >> 14;
    int t = rem & 16383;
    int j = t&7; int lane = (t>>3)&63; int blk = t>>9;
    int kc = blk>>3, nj = blk&7, ql = lane>>4, il = lane&15;
    int k = kc*32 + ql*8 + j;
    int gcol = il*8 + nj;
    const float* src = (f==0)?W1:((f==1)?W2:W3);
    float v = src[(size_t)l*16384 + k*128 + gcol];
    short hi = f2bs(v);
    float r1 = v - b2f(hi);
    short mi = f2bs(r1);
    short lo = f2bs(r1 - b2f(mi));
    Wffn[r0]        = *reinterpret_cast<__hip_bfloat16*>(&hi);
    Wffn[FT + r0]   = *reinterpret_cast<__hip_bfloat16*>(&mi);
    Wffn[2*FT + r0] = *reinterpret_cast<__hip_bfloat16*>(&lo);
  } else if(idx < QT+FT+BT){
    int j = idx - QT - FT;
    int l = j/640; int col = j - l*640;   // bias in NATURAL col order
    float v = 0.f;
    if(col<512){
      const float* src = (col<128)?bq:((col<256)?bk:((col<384)?bv:bsk));
      v = src[l*128 + (col&127)];
    } else if(col<552){
      int jj=col-512; int h=jj/10; int r=jj-10*h;
      const float* bqp = bq + l*128;
      const float* we = We + (size_t)l*1280 + r*128;
      float acc=0.f;
      for(int c=32*h;c<32*h+32;c++) acc = fmaf(bqp[c], we[c], acc);
      v = acc;
    }
    bqkvs[j] = v;
  }
}

// ---------------- LayerNorm (wave per node) fp32 -> fp32 (layer 0 only) ----------------
__global__ void ln_node(const float* __restrict__ h, const float* __restrict__ g,
                        const float* __restrict__ b, float* __restrict__ hn, int N){
  int n = blockIdx.x*4 + (threadIdx.x>>6);
  if(n>=N) return;
  int lane = threadIdx.x & 63;
  int c = 2*lane;
  float2 v = *(const float2*)&h[(size_t)n*HID + c];
  float s1 = wsum64(v.x+v.y);
  float s2 = wsum64(v.x*v.x+v.y*v.y);
  float mu = s1*(1.f/HID);
  float var = s2*(1.f/HID) - mu*mu;
  float rs = rsqrtf(var + 1e-5f);
  float2 o;
  o.x = (v.x-mu)*rs*g[c]   + b[c];
  o.y = (v.y-mu)*rs*g[c+1] + b[c+1];
  *(float2*)&hn[(size_t)n*HID + c] = o;
}

// 6-term triple-split MFMA accumulate (fixed order -> deterministic)
#define MFMA6(ACC, AH, AM, AL, BH, BM, BL)                                    \
  ACC = __builtin_amdgcn_mfma_f32_16x16x32_bf16(AH, BH, ACC, 0,0,0);          \
  ACC = __builtin_amdgcn_mfma_f32_16x16x32_bf16(AM, BH, ACC, 0,0,0);          \
  ACC = __builtin_amdgcn_mfma_f32_16x16x32_bf16(AH, BM, ACC, 0,0,0);          \
  ACC = __builtin_amdgcn_mfma_f32_16x16x32_bf16(AL, BH, ACC, 0,0,0);          \
  ACC = __builtin_amdgcn_mfma_f32_16x16x32_bf16(AM, BM, ACC, 0,0,0);          \
  ACC = __builtin_amdgcn_mfma_f32_16x16x32_bf16(AH, BL, ACC, 0,0,0);

// ---------------- qkvs GEMM: triple-split, W direct from L2, fp32 in/out ----------------
__global__ __launch_bounds__(256) void gemm_qkvs(
    const float* __restrict__ A, const __hip_bfloat16* __restrict__ Whi,
    const __hip_bfloat16* __restrict__ Wmi, const __hip_bfloat16* __restrict__ Wlo,
    const float* __restrict__ bias,
    float* __restrict__ qsO, float* __restrict__ kvO,
    float* __restrict__ qwO, int N){
  int row0 = blockIdx.y*128;
  int cb = blockIdx.x;
  int tid = threadIdx.x;
  int lane = tid&63;
  int m0 = (tid>>6)*32;
  int ql = lane>>4, il = lane&15;
  const __hip_bfloat16* Wh = Whi + (size_t)cb*16384;
  const __hip_bfloat16* Wm = Wmi + (size_t)cb*16384;
  const __hip_bfloat16* Wl = Wlo + (size_t)cb*16384;
  bf16x8 ah[2][4], am[2][4], al[2][4];
  #pragma unroll
  for(int mi2=0;mi2<2;mi2++){
    int r = row0 + m0 + mi2*16 + il;
    r = (r < N) ? r : (N-1);
    const float* ap = A + (size_t)r*128 + ql*8;
    #pragma unroll
    for(int kc=0;kc<4;kc++){
      float a8[8];
      float4 a0 = *(const float4*)(ap + kc*32);
      float4 a1 = *(const float4*)(ap + kc*32 + 4);
      a8[0]=a0.x;a8[1]=a0.y;a8[2]=a0.z;a8[3]=a0.w;
      a8[4]=a1.x;a8[5]=a1.y;a8[6]=a1.z;a8[7]=a1.w;
      split3_8(a8, ah[mi2][kc], am[mi2][kc], al[mi2][kc]);
    }
  }
  f32x4 acc[2][8];
  #pragma unroll
  for(int mi2=0;mi2<2;mi2++)
    #pragma unroll
    for(int nj=0;nj<8;nj++) acc[mi2][nj] = (f32x4){0.f,0.f,0.f,0.f};
  #pragma unroll
  for(int kc=0;kc<4;kc++){
    #pragma unroll
    for(int nj=0;nj<8;nj++){
      size_t bo = (size_t)((kc*8+nj)*64 + lane)*8;
      bf16x8 bh = *(const bf16x8*)&Wh[bo];
      bf16x8 bm = *(const bf16x8*)&Wm[bo];
      bf16x8 bl = *(const bf16x8*)&Wl[bo];
      #pragma unroll
      for(int mi2=0;mi2<2;mi2++){
        MFMA6(acc[mi2][nj], ah[mi2][kc], am[mi2][kc], al[mi2][kc], bh, bm, bl)
      }
    }
  }
  float bl8[8];
  {
    float4 b0 = *(const float4*)&bias[cb*128 + il*8];
    float4 b1 = *(const float4*)&bias[cb*128 + il*8 + 4];
    bl8[0]=b0.x; bl8[1]=b0.y; bl8[2]=b0.z; bl8[3]=b0.w;
    bl8[4]=b1.x; bl8[5]=b1.y; bl8[6]=b1.z; bl8[7]=b1.w;
  }
  #pragma unroll
  for(int mi2=0;mi2<2;mi2++){
    #pragma unroll
    for(int r=0;r<4;r++){
      int rr = row0 + m0 + mi2*16 + ql*4 + r;
      if(rr >= N) continue;
      if(cb < 4){
        float o8[8];
        #pragma unroll
        for(int nj=0;nj<8;nj++) o8[nj] = acc[mi2][nj][r] + bl8[nj];
        float* dst;
        if(cb==0)      dst = qsO + (size_t)rr*256 + il*8;          // q
        else if(cb==1) dst = kvO + (size_t)rr*256 + il*8;          // k
        else if(cb==2) dst = kvO + (size_t)rr*256 + 128 + il*8;    // v
        else           dst = qsO + (size_t)rr*256 + 128 + il*8;    // skip
        *(float4*)dst     = make_float4(o8[0],o8[1],o8[2],o8[3]);
        *(float4*)(dst+4) = make_float4(o8[4],o8[5],o8[6],o8[7]);
      } else if(il < 5){
        #pragma unroll
        for(int nj=0;nj<8;nj++){
          int g = il*8 + nj;            // < 40
          int h = g/10, rb = g - 10*h;
          qwO[(size_t)rr*48 + h*12 + rb] = acc[mi2][nj][r] + bl8[nj];
        }
      }
    }
  }
}

// ---------------- attention core: fp32 gathers, no-max softmax, aggregation ----------------
__global__ __launch_bounds__(256) void attn_fused7(
    const float* __restrict__ qs, const float* __restrict__ kvb,
    const float* __restrict__ qwb, const float* __restrict__ efs,
    const int* __restrict__ esrc, const float* __restrict__ WeL,
    const int* __restrict__ rowst, float* __restrict__ att, int N){
  int n = blockIdx.x*4 + (threadIdx.x>>6);
  if(n>=N) return;
  int lane = threadIdx.x & 63;
  int eg = lane>>4, sl = lane&15;
  int c8 = sl*8, hd = sl>>2;
  const float* rowq = qs + (size_t)n*256;
  float q8[8];
  {
    float4 q0 = *(const float4*)&rowq[c8];
    float4 q1 = *(const float4*)&rowq[c8+4];
    q8[0]=q0.x;q8[1]=q0.y;q8[2]=q0.z;q8[3]=q0.w;
    q8[4]=q1.x;q8[5]=q1.y;q8[6]=q1.z;q8[7]=q1.w;
  }
  const float* qwp = qwb + (size_t)n*48 + hd*12;
  float4 qa = *(const float4*)qwp;
  float4 qb = *(const float4*)(qwp+4);
  float2 qc = *(const float2*)(qwp+8);
  float QW[10] = {qa.x,qa.y,qa.z,qa.w,qb.x,qb.y,qb.z,qb.w,qc.x,qc.y};
  int lo = rowst[n], hi = rowst[n+1];
  float ssum = 0.f, a8[8], S[10];
  #pragma unroll
  for(int j=0;j<8;j++) a8[j]=0.f;
  #pragma unroll
  for(int r=0;r<10;r++) S[r]=0.f;
  for(int i=lo+eg; i<hi; i+=4){
    int s = esrc[i];
    const float* kr = kvb + (size_t)s*256;
    float4 k0 = *(const float4*)&kr[c8];
    float4 k1 = *(const float4*)&kr[c8+4];
    float4 v0 = *(const float4*)&kr[128+c8];
    float4 v1 = *(const float4*)&kr[128+c8+4];
    const float* ef = efs + (size_t)i*12;
    float4 e0 = *(const float4*)&ef[0];
    float4 e1 = *(const float4*)&ef[4];
    float2 e2 = *(const float2*)&ef[8];
    float d = q8[0]*k0.x + q8[1]*k0.y + q8[2]*k0.z + q8[3]*k0.w
            + q8[4]*k1.x + q8[5]*k1.y + q8[6]*k1.z + q8[7]*k1.w;
    d += __shfl_xor(d,1,64); d += __shfl_xor(d,2,64);   // per-head (quad) dot
    float lg = d;
    lg = fmaf(e0.x,QW[0],lg); lg = fmaf(e0.y,QW[1],lg);
    lg = fmaf(e0.z,QW[2],lg); lg = fmaf(e0.w,QW[3],lg);
    lg = fmaf(e1.x,QW[4],lg); lg = fmaf(e1.y,QW[5],lg);
    lg = fmaf(e1.z,QW[6],lg); lg = fmaf(e1.w,QW[7],lg);
    lg = fmaf(e2.x,QW[8],lg); lg = fmaf(e2.y,QW[9],lg);
    lg *= 0.17677669529663687f;
    lg = fminf(lg, 80.f);
    float w = __expf(lg);
    ssum += w;
    a8[0]=fmaf(w,v0.x,a8[0]); a8[1]=fmaf(w,v0.y,a8[1]);
    a8[2]=fmaf(w,v0.z,a8[2]); a8[3]=fmaf(w,v0.w,a8[3]);
    a8[4]=fmaf(w,v1.x,a8[4]); a8[5]=fmaf(w,v1.y,a8[5]);
    a8[6]=fmaf(w,v1.z,a8[6]); a8[7]=fmaf(w,v1.w,a8[7]);
    S[0]=fmaf(w,e0.x,S[0]); S[1]=fmaf(w,e0.y,S[1]); S[2]=fmaf(w,e0.z,S[2]);
    S[3]=fmaf(w,e0.w,S[3]); S[4]=fmaf(w,e1.x,S[4]); S[5]=fmaf(w,e1.y,S[5]);
    S[6]=fmaf(w,e1.z,S[6]); S[7]=fmaf(w,e1.w,S[7]); S[8]=fmaf(w,e2.x,S[8]);
    S[9]=fmaf(w,e2.y,S[9]);
  }
  float o8[8];
  #pragma unroll
  for(int j=0;j<8;j++) o8[j]=a8[j];
  #pragma unroll
  for(int r=0;r<10;r++){
    float s=S[r];
    float4 wa = *(const float4*)&WeL[r*128+c8];
    float4 wb = *(const float4*)&WeL[r*128+c8+4];
    o8[0]=fmaf(s,wa.x,o8[0]); o8[1]=fmaf(s,wa.y,o8[1]);
    o8[2]=fmaf(s,wa.z,o8[2]); o8[3]=fmaf(s,wa.w,o8[3]);
    o8[4]=fmaf(s,wb.x,o8[4]); o8[5]=fmaf(s,wb.y,o8[5]);
    o8[6]=fmaf(s,wb.z,o8[6]); o8[7]=fmaf(s,wb.w,o8[7]);
  }
  #pragma unroll
  for(int m=16;m<64;m<<=1){
    ssum += __shfl_xor(ssum,m,64);
    #pragma unroll
    for(int j=0;j<8;j++) o8[j] += __shfl_xor(o8[j],m,64);
  }
  if(eg==0){
    float inv = (hi>lo)? 1.f/ssum : 0.f;
    float4 v0 = make_float4(o8[0]*inv, o8[1]*inv, o8[2]*inv, o8[3]*inv);
    float4 v1 = make_float4(o8[4]*inv, o8[5]*inv, o8[6]*inv, o8[7]*inv);
    *(float4*)&att[(size_t)n*128 + c8]     = v0;
    *(float4*)&att[(size_t)n*128 + c8 + 4] = v1;
  }
}

// ---------------- beta-gate + residual + softplus + LN (fp32; hn2 -> qs q-region) ----------------
__global__ void combine_ln(const float* __restrict__ att, float* __restrict__ qs,
                           const float* __restrict__ hn, const float* __restrict__ Wb,
                           const float* __restrict__ g, const float* __restrict__ b,
                           int N){
  int n = blockIdx.x*4 + (threadIdx.x>>6);
  if(n>=N) return;
  int lane = threadIdx.x&63;
  int c = 2*lane;
  float2 o  = *(const float2*)&att[(size_t)n*HID+c];
  float2 xr = *(const float2*)&qs[(size_t)n*256 + 128 + c];
  float bl = o.x*Wb[c] + o.y*Wb[c+1]
           + xr.x*Wb[HID+c] + xr.y*Wb[HID+c+1]
           + (o.x-xr.x)*Wb[2*HID+c] + (o.y-xr.y)*Wb[2*HID+c+1];
  bl = wsum64(bl);
  float beta = sigm_(bl);
  float u0 = beta*xr.x + (1.f-beta)*o.x;
  float u1 = beta*xr.y + (1.f-beta)*o.y;
  float2 hnv = *(const float2*)&hn[(size_t)n*HID+c];
  float h0 = hnv.x + sp_(u0);
  float h1 = hnv.y + sp_(u1);
  float s1 = wsum64(h0+h1);
  float s2 = wsum64(h0*h0+h1*h1);
  float mu = s1*(1.f/HID);
  float var = s2*(1.f/HID)-mu*mu;
  float rs = rsqrtf(var+1e-5f);
  float2 outv;
  outv.x = (h0-mu)*rs*g[c]+b[c];
  outv.y = (h1-mu)*rs*g[c+1]+b[c+1];
  *(float2*)&qs[(size_t)n*256 + c] = outv;   // hn2 into qs's dead q-region
}

// ---------------- fused FFN: triple-split, W direct from L2, SINGLE fp32 LDS inter ----------------
// Each wave reads only its own 16 rows of inter (writes lr=wv*16+ql*4+r, reads
// row=wv*16+il), so one buffer serves both stage transitions. LDS 67.6->33.8KB
// => 4 blocks/CU. Numerics bit-identical to the two-buffer version.
__global__ __launch_bounds__(256) void ffn_fused(
    const float* __restrict__ hn2,
    const __hip_bfloat16* __restrict__ Wfhi, const __hip_bfloat16* __restrict__ Wfmi,
    const __hip_bfloat16* __restrict__ Wflo,
    const float* __restrict__ b1, const float* __restrict__ b2,
    const float* __restrict__ b3, const float* __restrict__ lng,
    const float* __restrict__ lnb, float* __restrict__ hout,
    float* __restrict__ hnout, int N){
  __shared__ float inter[64][IPADF];
  int row0 = blockIdx.x*64;
  int tid = threadIdx.x, lane = tid&63, wv = tid>>6;
  int ql = lane>>4, il = lane&15;

  auto loadbias = [&](const float* bp, float* bl8){
    float4 x0 = *(const float4*)&bp[il*8];
    float4 x1 = *(const float4*)&bp[il*8+4];
    bl8[0]=x0.x; bl8[1]=x0.y; bl8[2]=x0.z; bl8[3]=x0.w;
    bl8[4]=x1.x; bl8[5]=x1.y; bl8[6]=x1.z; bl8[7]=x1.w;
  };
  auto gemm_stage = [&](const __hip_bfloat16* Wh, const __hip_bfloat16* Wm,
                        const __hip_bfloat16* Wl,
                        bf16x8* ah, bf16x8* am, bf16x8* al, f32x4* acc){
    #pragma unroll
    for(int nj=0;nj<8;nj++) acc[nj] = (f32x4){0.f,0.f,0.f,0.f};
    #pragma unroll
    for(int kc=0;kc<4;kc++)
      #pragma unroll
      for(int nj=0;nj<8;nj++){
        size_t bo = (size_t)((kc*8+nj)*64 + lane)*8;
        bf16x8 bh = *(const bf16x8*)&Wh[bo];
        bf16x8 bm = *(const bf16x8*)&Wm[bo];
        bf16x8 bl = *(const bf16x8*)&Wl[bo];
        MFMA6(acc[nj], ah[kc], am[kc], al[kc], bh, bm, bl)
      }
  };
  auto store_inter = [&](const float* bp, f32x4* acc){
    float bl8[8]; loadbias(bp, bl8);
    #pragma unroll
    for(int r=0;r<4;r++){
      int lr = wv*16 + ql*4 + r;
      float o8[8];
      #pragma unroll
      for(int nj=0;nj<8;nj++) o8[nj] = sp_(acc[nj][r] + bl8[nj]);
      *(float4*)&inter[lr][il*8]   = make_float4(o8[0],o8[1],o8[2],o8[3]);
      *(float4*)&inter[lr][il*8+4] = make_float4(o8[4],o8[5],o8[6],o8[7]);
    }
  };
  auto load_afrag = [&](bf16x8* ah, bf16x8* am, bf16x8* al){
    #pragma unroll
    for(int kc=0;kc<4;kc++){
      float a8[8];
      float4 a0 = *(float4*)&inter[wv*16+il][ql*8 + kc*32];
      float4 a1 = *(float4*)&inter[wv*16+il][ql*8 + kc*32 + 4];
      a8[0]=a0.x;a8[1]=a0.y;a8[2]=a0.z;a8[3]=a0.w;
      a8[4]=a1.x;a8[5]=a1.y;a8[6]=a1.z;a8[7]=a1.w;
      split3_8(a8, ah[kc], am[kc], al[kc]);
    }
  };

  f32x4 acc[8];
  bf16x8 ah[4], am[4], al[4];
  // ---- FFN1 (A from global, stride 256: hn2 lives in qs q-region) ----
  {
    int r = row0 + wv*16 + il;
    r = (r<N)? r : (N-1);
    const float* ap = hn2 + (size_t)r*256 + ql*8;
    #pragma unroll
    for(int kc=0;kc<4;kc++){
      float a8[8];
      float4 a0 = *(const float4*)(ap + kc*32);
      float4 a1 = *(const float4*)(ap + kc*32 + 4);
      a8[0]=a0.x;a8[1]=a0.y;a8[2]=a0.z;a8[3]=a0.w;
      a8[4]=a1.x;a8[5]=a1.y;a8[6]=a1.z;a8[7]=a1.w;
      split3_8(a8, ah[kc], am[kc], al[kc]);
    }
  }
  gemm_stage(Wfhi, Wfmi, Wflo, ah, am, al, acc);
  store_inter(b1, acc);
  __syncthreads();
  // ---- FFN2 (A from inter) ----
  load_afrag(ah, am, al);
  __syncthreads();
  gemm_stage(Wfhi + 16384, Wfmi + 16384, Wflo + 16384, ah, am, al, acc);
  store_inter(b2, acc);
  __syncthreads();
  // ---- FFN3 (A from inter) + epilogue ----
  load_afrag(ah, am, al);
  gemm_stage(Wfhi + 2*16384, Wfmi + 2*16384, Wflo + 2*16384, ah, am, al, acc);
  {
    float bl8[8]; loadbias(b3, bl8);
    float lg8[8], lb8[8];
    loadbias(lng, lg8); loadbias(lnb, lb8);
    #pragma unroll
    for(int r=0;r<4;r++){
      int rr = row0 + wv*16 + ql*4 + r;
      if(rr >= N) continue;     // uniform across il -> shfl-safe
      float rv8[8];
      {
        const float* rp = hn2 + (size_t)rr*256 + il*8;
        float4 r0 = *(const float4*)rp;
        float4 r1 = *(const float4*)(rp+4);
        rv8[0]=r0.x;rv8[1]=r0.y;rv8[2]=r0.z;rv8[3]=r0.w;
        rv8[4]=r1.x;rv8[5]=r1.y;rv8[6]=r1.z;rv8[7]=r1.w;
      }
      float t8[8], s1=0.f, s2=0.f;
      #pragma unroll
      for(int nj=0;nj<8;nj++){
        float x = sp_(acc[nj][r] + bl8[nj]) + rv8[nj];
        t8[nj]=x; s1+=x; s2+=x*x;
      }
      s1 = wsum16(s1); s2 = wsum16(s2);
      float mu = s1*(1.f/128.f);
      float var = s2*(1.f/128.f) - mu*mu;
      float rsg = rsqrtf(var + 1e-5f);
      *(float4*)&hout[(size_t)rr*128 + il*8]     = make_float4(t8[0],t8[1],t8[2],t8[3]);
      *(float4*)&hout[(size_t)rr*128 + il*8 + 4] = make_float4(t8[4],t8[5],t8[6],t8[7]);
      float o8[8];
      #pragma unroll
      for(int nj=0;nj<8;nj++) o8[nj] = (t8[nj]-mu)*rsg*lg8[nj] + lb8[nj];
      *(float4*)&hnout[(size_t)rr*128 + il*8]     = make_float4(o8[0],o8[1],o8[2],o8[3]);
      *(float4*)&hnout[(size_t)rr*128 + il*8 + 4] = make_float4(o8[4],o8[5],o8[6],o8[7]);
    }
  }
}

// ---------------- pooling + output head (block per graph) ----------------
__global__ void pool_head(const float* __restrict__ h, const int* __restrict__ batch,
                          const float* __restrict__ Wo1, const float* __restrict__ bo1,
                          const float* __restrict__ Wo2, const float* __restrict__ bo2,
                          float* __restrict__ out, int N){
  int gid = blockIdx.x;
  int t = threadIdx.x;  // 128 threads
  int lo = lb_(batch, N, gid), hi = lb_(batch, N, gid+1);
  __shared__ float pl[128];
  __shared__ float red[128];
  float s = 0.f;
  for(int i=lo;i<hi;i++) s += h[(size_t)i*HID + t];
  pl[t] = s;
  __syncthreads();
  float acc = bo1[t];
  for(int c=0;c<128;c++) acc = fmaf(pl[c], Wo1[c*HID+t], acc);
  red[t] = sp_(acc)*Wo2[t];
  __syncthreads();
  for(int off=64;off>0;off>>=1){
    if(t<off) red[t]+=red[t+off];
    __syncthreads();
  }
  if(t==0) out[gid] = red[0] + bo2[0];
}

extern "C" void kernel_launch(void* const* d_in, const int* in_sizes, int n_in,
                              void* d_out, int out_size, void* d_ws, size_t ws_size,
                              hipStream_t stream){
  const float* h_in = (const float*)d_in[0];
  const float* pos  = (const float*)d_in[1];
  const float* ew   = (const float*)d_in[2];
  const float* Wq = (const float*)d_in[3];  const float* bq = (const float*)d_in[4];
  const float* Wk = (const float*)d_in[5];  const float* bk = (const float*)d_in[6];
  const float* Wv = (const float*)d_in[7];  const float* bv = (const float*)d_in[8];
  const float* We = (const float*)d_in[9];
  const float* Wsk= (const float*)d_in[10]; const float* bsk=(const float*)d_in[11];
  const float* Wbeta=(const float*)d_in[12];
  const float* W1=(const float*)d_in[13]; const float* b1=(const float*)d_in[14];
  const float* W2=(const float*)d_in[15]; const float* b2=(const float*)d_in[16];
  const float* W3=(const float*)d_in[17]; const float* b3=(const float*)d_in[18];
  const float* lng=(const float*)d_in[19]; const float* lnb=(const float*)d_in[20];
  const float* Wo1=(const float*)d_in[21]; const float* bo1=(const float*)d_in[22];
  const float* Wo2=(const float*)d_in[23]; const float* bo2=(const float*)d_in[24];
  const int* ei    = (const int*)d_in[25];
  const int* batch = (const int*)d_in[26];
  int N = in_sizes[0]/HID;
  int E = in_sizes[2];
  int G = out_size;
  float* out = (float*)d_out;

  char* ws = (char*)d_ws;
  size_t off=0;
  auto alloc=[&](size_t bytes)->char*{
    char* p = ws + off;
    off = (off + bytes + 255) & ~(size_t)255;
    return p;
  };
  float* efs   =(float*)alloc((size_t)E*12*4);
  int* esrc    =(int*)  alloc((size_t)E*4);
  int* csr     =(int*)  alloc((size_t)E*4);
  int* counts  =(int*)  alloc((size_t)N*4);
  int* counts2 =(int*)  alloc((size_t)N*4);
  int* rowst   =(int*)  alloc((size_t)(N+1)*4);
  int* tmp     =(int*)  alloc((size_t)N*4);
  int* bsums   =(int*)  alloc(256*4);
  int* boffs   =(int*)  alloc(256*4);
  float* hnf   =(float*)alloc((size_t)N*HID*4);      // LN(h) fp32
  float* qsb   =(float*)alloc((size_t)N*256*4);      // q | skip (q-region reused as hn2)
  float* kvb   =(float*)alloc((size_t)N*256*4);      // k | v
  float* qwb   =(float*)alloc((size_t)N*48*4);
  float* att   =(float*)alloc((size_t)N*HID*4);
  float* hcur  =(float*)alloc((size_t)N*HID*4);
  __hip_bfloat16* Wqkvs_t =(__hip_bfloat16*)alloc((size_t)3*NLAYER*5*16384*2);  // hi|mid|lo
  __hip_bfloat16* Wffn_t  =(__hip_bfloat16*)alloc((size_t)3*NLAYER*3*16384*2);  // hi|mid|lo
  float* bqkvs =(float*)alloc((size_t)NLAYER*640*4);
  size_t ws_used = off;

  const int QT = NLAYER*5*16384;
  const int FT = NLAYER*3*16384;
  int ebl = (E+255)/256;
  int nb  = (N+255)/256;
  int nwb = (N+3)/4;
  int nrb128 = (N+127)/128;
  int nrb64  = (N+63)/64;
  dim3 gqkvs(5, nrb128);

  // Normalize workspace state inside the captured graph (consistent launches).
  hipMemsetAsync(ws, 0, (ws_used <= ws_size ? ws_used : ws_size), stream);

  count_dst<<<ebl,256,0,stream>>>(ei,counts,E);
  scan1<<<nb,256,0,stream>>>(counts,tmp,bsums,N);
  scan2<<<1,256,0,stream>>>(bsums,boffs,nb);
  finalize_rs<<<nb,256,0,stream>>>(tmp,boffs,rowst,N);
  csr_scatter<<<ebl,256,0,stream>>>(ei,rowst,counts2,csr,E);
  sort_seg<<<nb,256,0,stream>>>(rowst,csr,N);          // deterministic order
  edge_feat<<<ebl,256,0,stream>>>(pos,ew,ei,csr,efs,esrc,E);
  {
    int tot = QT + FT + NLAYER*640;
    pack_w<<<(tot+255)/256,256,0,stream>>>(Wq,Wk,Wv,Wsk,bq,bk,bv,bsk,We,W1,W2,W3,
                                           Wqkvs_t,bqkvs,Wffn_t);
  }

  ln_node<<<nwb,256,0,stream>>>(h_in,lng,lnb,hnf,N);
  for(int l=0;l<NLAYER;l++){
    const float* We_l = We + (size_t)l*(KRBF+1)*HID;
    const float* Wb_l = Wbeta + (size_t)l*3*HID;
    const float* b1_l = b1 + (size_t)l*HID;
    const float* b2_l = b2 + (size_t)l*HID;
    const float* b3_l = b3 + (size_t)l*HID;
    const __hip_bfloat16* Wq_hi = Wqkvs_t + (size_t)l*5*16384;
    const __hip_bfloat16* Wq_mi = Wqkvs_t + QT + (size_t)l*5*16384;
    const __hip_bfloat16* Wq_lo = Wqkvs_t + 2*(size_t)QT + (size_t)l*5*16384;
    const __hip_bfloat16* Wf_hi = Wffn_t + (size_t)l*3*16384;
    const __hip_bfloat16* Wf_mi = Wffn_t + FT + (size_t)l*3*16384;
    const __hip_bfloat16* Wf_lo = Wffn_t + 2*(size_t)FT + (size_t)l*3*16384;

    gemm_qkvs<<<gqkvs,256,0,stream>>>(hnf, Wq_hi, Wq_mi, Wq_lo, bqkvs + l*640,
                                      qsb, kvb, qwb, N);
    attn_fused7<<<nwb,256,0,stream>>>(qsb,kvb,qwb,efs,esrc,We_l,rowst,att,N);
    combine_ln<<<nwb,256,0,stream>>>(att,qsb,hnf,Wb_l,lng,lnb,N);
    ffn_fused<<<nrb64,256,0,stream>>>(qsb, Wf_hi, Wf_mi, Wf_lo,
                                      b1_l,b2_l,b3_l,lng,lnb,hcur,hnf,N);
  }
  pool_head<<<G,128,0,stream>>>(hcur,batch,Wo1,bo1,Wo2,bo2,out,N);
}

// Round 17
// 987.037 us; speedup vs baseline: 1.0179x; 1.0179x over previous
//
#include <hip/hip_runtime.h>
#include <hip/hip_bf16.h>
#include <math.h>

#define HID 128
#define KRBF 9
#define NLAYER 3
#define IPADF 132   // fp32 inter LDS row stride (floats): 528B, 16B-aligned rows

typedef __attribute__((ext_vector_type(8))) short bf16x8;
typedef __attribute__((ext_vector_type(4))) float f32x4;

// fast softplus: abs err ~1e-7 (amplifies to ~2e-3 at output — safe)
__device__ __forceinline__ float sp_(float x){
  return fmaxf(x,0.f) + __logf(1.f + __expf(-fabsf(x)));
}
__device__ __forceinline__ float sigm_(float x){ return 1.f/(1.f+__expf(-x)); }
__device__ __forceinline__ float b2f(short s){
  union{unsigned u; float f;} x; x.u = ((unsigned)(unsigned short)s)<<16; return x.f;
}
__device__ __forceinline__ short f2bs(float x){
  __hip_bfloat16 b = __float2bfloat16(x);
  return *reinterpret_cast<short*>(&b);
}
// triple split fp32 -> bf16 hi+mid+lo (x ~= h+m+l, residual ~6e-8 rel)
__device__ __forceinline__ void split3_8(const float* a, bf16x8& hi, bf16x8& mi, bf16x8& lo){
  #pragma unroll
  for(int j=0;j<8;j++){
    float x = a[j];
    short h = f2bs(x); hi[j]=h;
    float r1 = x - b2f(h);
    short m = f2bs(r1); mi[j]=m;
    lo[j] = f2bs(r1 - b2f(m));
  }
}
__device__ __forceinline__ float wsum64(float v){
  #pragma unroll
  for(int m=1;m<64;m<<=1) v += __shfl_xor(v,m,64);
  return v;
}
__device__ __forceinline__ float wsum16(float v){
  #pragma unroll
  for(int m=1;m<16;m<<=1) v += __shfl_xor(v,m,64);
  return v;
}
__device__ __forceinline__ int lb_(const int* __restrict__ a, int n, int key){
  int lo=0, hi=n;
  while(lo<hi){ int mid=(lo+hi)>>1; if(a[mid]<key) lo=mid+1; else hi=mid; }
  return lo;
}

// ---------------- CSR ----------------
__global__ void count_dst(const int* __restrict__ ei, int* __restrict__ counts, int E){
  int e = blockIdx.x*256+threadIdx.x;
  if(e<E) atomicAdd(&counts[ei[E+e]],1);
}
__global__ void scan1(const int* __restrict__ counts, int* __restrict__ tmp,
                      int* __restrict__ bsums, int N){
  __shared__ int lds[256];
  int t = threadIdx.x; int idx = blockIdx.x*256+t;
  int v = (idx<N)? counts[idx]:0;
  lds[t]=v; __syncthreads();
  for(int off=1;off<256;off<<=1){
    int x = (t>=off)? lds[t-off]:0;
    __syncthreads();
    lds[t]+=x; __syncthreads();
  }
  if(idx<N) tmp[idx]=lds[t];
  if(t==255) bsums[blockIdx.x]=lds[255];
}
__global__ void scan2(const int* __restrict__ bsums, int* __restrict__ boffs, int nb){
  __shared__ int lds[256];
  int t=threadIdx.x;
  int v = (t<nb)? bsums[t]:0;
  lds[t]=v; __syncthreads();
  for(int off=1;off<256;off<<=1){
    int x=(t>=off)?lds[t-off]:0;
    __syncthreads();
    lds[t]+=x; __syncthreads();
  }
  if(t<nb) boffs[t] = lds[t]-v; // exclusive
}
__global__ void finalize_rs(const int* __restrict__ tmp, const int* __restrict__ boffs,
                            int* __restrict__ row_start, int N){
  int idx = blockIdx.x*256+threadIdx.x;
  if(idx<N) row_start[idx+1] = tmp[idx] + boffs[idx>>8];
  if(idx==0) row_start[0]=0;
}
__global__ void csr_scatter(const int* __restrict__ ei, const int* __restrict__ rowst,
                            int* __restrict__ counts2, int* __restrict__ csr, int E){
  int e = blockIdx.x*256+threadIdx.x;
  if(e>=E) return;
  int d = ei[E+e];
  int p = rowst[d] + atomicAdd(&counts2[d],1);
  csr[p] = e;
}
// deterministic segment order: insertion-sort each node's edge ids ascending
__global__ void sort_seg(const int* __restrict__ rowst, int* __restrict__ csr, int N){
  int n = blockIdx.x*256+threadIdx.x;
  if(n>=N) return;
  int lo=rowst[n], hi=rowst[n+1];
  for(int i=lo+1;i<hi;i++){
    int v=csr[i]; int j=i-1;
    while(j>=lo && csr[j]>v){ csr[j+1]=csr[j]; j--; }
    csr[j+1]=v;
  }
}
__global__ void edge_feat(const float* __restrict__ pos, const float* __restrict__ ew,
                          const int* __restrict__ ei, const int* __restrict__ csr,
                          float* __restrict__ efs, int* __restrict__ esrc, int E){
  int p = blockIdx.x*256 + threadIdx.x;
  if(p>=E) return;
  int e = csr[p];
  int s = ei[e], d = ei[E+e];
  float dx = pos[d*3+0]-pos[s*3+0];
  float dy = pos[d*3+1]-pos[s*3+1];
  float dz = pos[d*3+2]-pos[s*3+2];
  float D = sqrtf(dx*dx+dy*dy+dz*dz);
  float x = D*0.1f;
  float cut = 0.f;
  if(x < 1.f){ float x3=x*x*x, x4=x3*x, x5=x4*x; cut = 1.f - 6.f*x5 + 15.f*x4 - 10.f*x3; }
  float ed = expf(-D);
  const double e10 = 4.5399929762484854e-05; // exp(-10)
  const float step  = (float)((e10 - 1.0)/8.0);
  const float width = (float)((4.5/(1.0-e10))*(4.5/(1.0-e10)));
  float r12[12];
  #pragma unroll
  for(int k=0;k<KRBF;k++){
    float c = 1.0f + k*step;
    float dd = ed - c;
    r12[k] = cut*expf(-width*dd*dd);
  }
  r12[9] = ew[e]; r12[10]=0.f; r12[11]=0.f;
  float* o = efs + (size_t)p*12;
  *(float4*)&o[0] = *(float4*)&r12[0];
  *(float4*)&o[4] = *(float4*)&r12[4];
  *(float4*)&o[8] = *(float4*)&r12[8];
  esrc[p] = s;
}

// ---------------- weight packing: fragment-flat, TRIPLE-split bf16 planes ----------------
// planes at [0,T), [T,2T), [2T,3T)
__global__ void pack_w(const float* __restrict__ Wq, const float* __restrict__ Wk,
                       const float* __restrict__ Wv, const float* __restrict__ Wsk,
                       const float* __restrict__ bq, const float* __restrict__ bk,
                       const float* __restrict__ bv, const float* __restrict__ bsk,
                       const float* __restrict__ We,
                       const float* __restrict__ W1, const float* __restrict__ W2,
                       const float* __restrict__ W3,
                       __hip_bfloat16* __restrict__ Wqkvs, float* __restrict__ bqkvs,
                       __hip_bfloat16* __restrict__ Wffn){
  int idx = blockIdx.x*256 + threadIdx.x;
  const int QT = NLAYER*5*16384;
  const int FT = NLAYER*3*16384;
  const int BT = NLAYER*640;
  if(idx < QT){
    int l = idx / (5*16384);
    int rem = idx - l*(5*16384);
    int cb = rem >> 14;
    int t = rem & 16383;
    int j = t&7; int lane = (t>>3)&63; int blk = t>>9;
    int kc = blk>>3, nj = blk&7, ql = lane>>4, il = lane&15;
    int k = kc*32 + ql*8 + j;
    int gcol = cb*128 + il*8 + nj;
    float v = 0.f;
    if(gcol < 512){
      const float* src = (gcol<128)?Wq:((gcol<256)?Wk:((gcol<384)?Wv:Wsk));
      v = src[(size_t)l*16384 + k*128 + (gcol&127)];
    } else if(gcol < 552){
      int jj = gcol-512; int h=jj/10; int r=jj-10*h;
      const float* wq = Wq + (size_t)l*16384 + k*128;
      const float* we = We + (size_t)l*1280 + r*128;
      float acc=0.f;
      #pragma unroll 8
      for(int c=32*h;c<32*h+32;c++) acc = fmaf(wq[c], we[c], acc);
      v = acc;
    }
    short hi = f2bs(v);
    float r1 = v - b2f(hi);
    short mi = f2bs(r1);
    short lo = f2bs(r1 - b2f(mi));
    Wqkvs[idx]        = *reinterpret_cast<__hip_bfloat16*>(&hi);
    Wqkvs[QT + idx]   = *reinterpret_cast<__hip_bfloat16*>(&mi);
    Wqkvs[2*QT + idx] = *reinterpret_cast<__hip_bfloat16*>(&lo);
  } else if(idx < QT+FT){
    int r0 = idx - QT;
    int l = r0 / (3*16384);
    int rem = r0 - l*(3*16384);
    int f = rem >> 14;
    int t = rem & 16383;
    int j = t&7; int lane = (t>>3)&63; int blk = t>>9;
    int kc = blk>>3, nj = blk&7, ql = lane>>4, il = lane&15;
    int k = kc*32 + ql*8 + j;
    int gcol = il*8 + nj;
    const float* src = (f==0)?W1:((f==1)?W2:W3);
    float v = src[(size_t)l*16384 + k*128 + gcol];
    short hi = f2bs(v);
    float r1 = v - b2f(hi);
    short mi = f2bs(r1);
    short lo = f2bs(r1 - b2f(mi));
    Wffn[r0]        = *reinterpret_cast<__hip_bfloat16*>(&hi);
    Wffn[FT + r0]   = *reinterpret_cast<__hip_bfloat16*>(&mi);
    Wffn[2*FT + r0] = *reinterpret_cast<__hip_bfloat16*>(&lo);
  } else if(idx < QT+FT+BT){
    int j = idx - QT - FT;
    int l = j/640; int col = j - l*640;   // bias in NATURAL col order
    float v = 0.f;
    if(col<512){
      const float* src = (col<128)?bq:((col<256)?bk:((col<384)?bv:bsk));
      v = src[l*128 + (col&127)];
    } else if(col<552){
      int jj=col-512; int h=jj/10; int r=jj-10*h;
      const float* bqp = bq + l*128;
      const float* we = We + (size_t)l*1280 + r*128;
      float acc=0.f;
      for(int c=32*h;c<32*h+32;c++) acc = fmaf(bqp[c], we[c], acc);
      v = acc;
    }
    bqkvs[j] = v;
  }
}

// ---------------- LayerNorm (wave per node) fp32 -> fp32 (layer 0 only) ----------------
__global__ void ln_node(const float* __restrict__ h, const float* __restrict__ g,
                        const float* __restrict__ b, float* __restrict__ hn, int N){
  int n = blockIdx.x*4 + (threadIdx.x>>6);
  if(n>=N) return;
  int lane = threadIdx.x & 63;
  int c = 2*lane;
  float2 v = *(const float2*)&h[(size_t)n*HID + c];
  float s1 = wsum64(v.x+v.y);
  float s2 = wsum64(v.x*v.x+v.y*v.y);
  float mu = s1*(1.f/HID);
  float var = s2*(1.f/HID) - mu*mu;
  float rs = rsqrtf(var + 1e-5f);
  float2 o;
  o.x = (v.x-mu)*rs*g[c]   + b[c];
  o.y = (v.y-mu)*rs*g[c+1] + b[c+1];
  *(float2*)&hn[(size_t)n*HID + c] = o;
}

// 6-term triple-split MFMA accumulate (fixed order -> deterministic)
#define MFMA6(ACC, AH, AM, AL, BH, BM, BL)                                    \
  ACC = __builtin_amdgcn_mfma_f32_16x16x32_bf16(AH, BH, ACC, 0,0,0);          \
  ACC = __builtin_amdgcn_mfma_f32_16x16x32_bf16(AM, BH, ACC, 0,0,0);          \
  ACC = __builtin_amdgcn_mfma_f32_16x16x32_bf16(AH, BM, ACC, 0,0,0);          \
  ACC = __builtin_amdgcn_mfma_f32_16x16x32_bf16(AL, BH, ACC, 0,0,0);          \
  ACC = __builtin_amdgcn_mfma_f32_16x16x32_bf16(AM, BM, ACC, 0,0,0);          \
  ACC = __builtin_amdgcn_mfma_f32_16x16x32_bf16(AH, BL, ACC, 0,0,0);

// ---------------- qkvs GEMM: triple-split, W direct from L2, fp32 in/out ----------------
__global__ __launch_bounds__(256) void gemm_qkvs(
    const float* __restrict__ A, const __hip_bfloat16* __restrict__ Whi,
    const __hip_bfloat16* __restrict__ Wmi, const __hip_bfloat16* __restrict__ Wlo,
    const float* __restrict__ bias,
    float* __restrict__ qsO, float* __restrict__ kvO,
    float* __restrict__ qwO, int N){
  int row0 = blockIdx.y*128;
  int cb = blockIdx.x;
  int tid = threadIdx.x;
  int lane = tid&63;
  int m0 = (tid>>6)*32;
  int ql = lane>>4, il = lane&15;
  const __hip_bfloat16* Wh = Whi + (size_t)cb*16384;
  const __hip_bfloat16* Wm = Wmi + (size_t)cb*16384;
  const __hip_bfloat16* Wl = Wlo + (size_t)cb*16384;
  bf16x8 ah[2][4], am[2][4], al[2][4];
  #pragma unroll
  for(int mi2=0;mi2<2;mi2++){
    int r = row0 + m0 + mi2*16 + il;
    r = (r < N) ? r : (N-1);
    const float* ap = A + (size_t)r*128 + ql*8;
    #pragma unroll
    for(int kc=0;kc<4;kc++){
      float a8[8];
      float4 a0 = *(const float4*)(ap + kc*32);
      float4 a1 = *(const float4*)(ap + kc*32 + 4);
      a8[0]=a0.x;a8[1]=a0.y;a8[2]=a0.z;a8[3]=a0.w;
      a8[4]=a1.x;a8[5]=a1.y;a8[6]=a1.z;a8[7]=a1.w;
      split3_8(a8, ah[mi2][kc], am[mi2][kc], al[mi2][kc]);
    }
  }
  f32x4 acc[2][8];
  #pragma unroll
  for(int mi2=0;mi2<2;mi2++)
    #pragma unroll
    for(int nj=0;nj<8;nj++) acc[mi2][nj] = (f32x4){0.f,0.f,0.f,0.f};
  #pragma unroll
  for(int kc=0;kc<4;kc++){
    #pragma unroll
    for(int nj=0;nj<8;nj++){
      size_t bo = (size_t)((kc*8+nj)*64 + lane)*8;
      bf16x8 bh = *(const bf16x8*)&Wh[bo];
      bf16x8 bm = *(const bf16x8*)&Wm[bo];
      bf16x8 bl = *(const bf16x8*)&Wl[bo];
      #pragma unroll
      for(int mi2=0;mi2<2;mi2++){
        MFMA6(acc[mi2][nj], ah[mi2][kc], am[mi2][kc], al[mi2][kc], bh, bm, bl)
      }
    }
  }
  float bl8[8];
  {
    float4 b0 = *(const float4*)&bias[cb*128 + il*8];
    float4 b1 = *(const float4*)&bias[cb*128 + il*8 + 4];
    bl8[0]=b0.x; bl8[1]=b0.y; bl8[2]=b0.z; bl8[3]=b0.w;
    bl8[4]=b1.x; bl8[5]=b1.y; bl8[6]=b1.z; bl8[7]=b1.w;
  }
  #pragma unroll
  for(int mi2=0;mi2<2;mi2++){
    #pragma unroll
    for(int r=0;r<4;r++){
      int rr = row0 + m0 + mi2*16 + ql*4 + r;
      if(rr >= N) continue;
      if(cb < 4){
        float o8[8];
        #pragma unroll
        for(int nj=0;nj<8;nj++) o8[nj] = acc[mi2][nj][r] + bl8[nj];
        float* dst;
        if(cb==0)      dst = qsO + (size_t)rr*256 + il*8;          // q
        else if(cb==1) dst = kvO + (size_t)rr*256 + il*8;          // k
        else if(cb==2) dst = kvO + (size_t)rr*256 + 128 + il*8;    // v
        else           dst = qsO + (size_t)rr*256 + 128 + il*8;    // skip
        *(float4*)dst     = make_float4(o8[0],o8[1],o8[2],o8[3]);
        *(float4*)(dst+4) = make_float4(o8[4],o8[5],o8[6],o8[7]);
      } else if(il < 5){
        #pragma unroll
        for(int nj=0;nj<8;nj++){
          int g = il*8 + nj;            // < 40
          int h = g/10, rb = g - 10*h;
          qwO[(size_t)rr*48 + h*12 + rb] = acc[mi2][nj][r] + bl8[nj];
        }
      }
    }
  }
}

// ---------------- attention core: fp32 gathers, no-max softmax, aggregation ----------------
__global__ __launch_bounds__(256) void attn_fused7(
    const float* __restrict__ qs, const float* __restrict__ kvb,
    const float* __restrict__ qwb, const float* __restrict__ efs,
    const int* __restrict__ esrc, const float* __restrict__ WeL,
    const int* __restrict__ rowst, float* __restrict__ att, int N){
  int n = blockIdx.x*4 + (threadIdx.x>>6);
  if(n>=N) return;
  int lane = threadIdx.x & 63;
  int eg = lane>>4, sl = lane&15;
  int c8 = sl*8, hd = sl>>2;
  const float* rowq = qs + (size_t)n*256;
  float q8[8];
  {
    float4 q0 = *(const float4*)&rowq[c8];
    float4 q1 = *(const float4*)&rowq[c8+4];
    q8[0]=q0.x;q8[1]=q0.y;q8[2]=q0.z;q8[3]=q0.w;
    q8[4]=q1.x;q8[5]=q1.y;q8[6]=q1.z;q8[7]=q1.w;
  }
  const float* qwp = qwb + (size_t)n*48 + hd*12;
  float4 qa = *(const float4*)qwp;
  float4 qb = *(const float4*)(qwp+4);
  float2 qc = *(const float2*)(qwp+8);
  float QW[10] = {qa.x,qa.y,qa.z,qa.w,qb.x,qb.y,qb.z,qb.w,qc.x,qc.y};
  int lo = rowst[n], hi = rowst[n+1];
  float ssum = 0.f, a8[8], S[10];
  #pragma unroll
  for(int j=0;j<8;j++) a8[j]=0.f;
  #pragma unroll
  for(int r=0;r<10;r++) S[r]=0.f;
  for(int i=lo+eg; i<hi; i+=4){
    int s = esrc[i];
    const float* kr = kvb + (size_t)s*256;
    float4 k0 = *(const float4*)&kr[c8];
    float4 k1 = *(const float4*)&kr[c8+4];
    float4 v0 = *(const float4*)&kr[128+c8];
    float4 v1 = *(const float4*)&kr[128+c8+4];
    const float* ef = efs + (size_t)i*12;
    float4 e0 = *(const float4*)&ef[0];
    float4 e1 = *(const float4*)&ef[4];
    float2 e2 = *(const float2*)&ef[8];
    float d = q8[0]*k0.x + q8[1]*k0.y + q8[2]*k0.z + q8[3]*k0.w
            + q8[4]*k1.x + q8[5]*k1.y + q8[6]*k1.z + q8[7]*k1.w;
    d += __shfl_xor(d,1,64); d += __shfl_xor(d,2,64);   // per-head (quad) dot
    float lg = d;
    lg = fmaf(e0.x,QW[0],lg); lg = fmaf(e0.y,QW[1],lg);
    lg = fmaf(e0.z,QW[2],lg); lg = fmaf(e0.w,QW[3],lg);
    lg = fmaf(e1.x,QW[4],lg); lg = fmaf(e1.y,QW[5],lg);
    lg = fmaf(e1.z,QW[6],lg); lg = fmaf(e1.w,QW[7],lg);
    lg = fmaf(e2.x,QW[8],lg); lg = fmaf(e2.y,QW[9],lg);
    lg *= 0.17677669529663687f;
    lg = fminf(lg, 80.f);
    float w = __expf(lg);
    ssum += w;
    a8[0]=fmaf(w,v0.x,a8[0]); a8[1]=fmaf(w,v0.y,a8[1]);
    a8[2]=fmaf(w,v0.z,a8[2]); a8[3]=fmaf(w,v0.w,a8[3]);
    a8[4]=fmaf(w,v1.x,a8[4]); a8[5]=fmaf(w,v1.y,a8[5]);
    a8[6]=fmaf(w,v1.z,a8[6]); a8[7]=fmaf(w,v1.w,a8[7]);
    S[0]=fmaf(w,e0.x,S[0]); S[1]=fmaf(w,e0.y,S[1]); S[2]=fmaf(w,e0.z,S[2]);
    S[3]=fmaf(w,e0.w,S[3]); S[4]=fmaf(w,e1.x,S[4]); S[5]=fmaf(w,e1.y,S[5]);
    S[6]=fmaf(w,e1.z,S[6]); S[7]=fmaf(w,e1.w,S[7]); S[8]=fmaf(w,e2.x,S[8]);
    S[9]=fmaf(w,e2.y,S[9]);
  }
  float o8[8];
  #pragma unroll
  for(int j=0;j<8;j++) o8[j]=a8[j];
  #pragma unroll
  for(int r=0;r<10;r++){
    float s=S[r];
    float4 wa = *(const float4*)&WeL[r*128+c8];
    float4 wb = *(const float4*)&WeL[r*128+c8+4];
    o8[0]=fmaf(s,wa.x,o8[0]); o8[1]=fmaf(s,wa.y,o8[1]);
    o8[2]=fmaf(s,wa.z,o8[2]); o8[3]=fmaf(s,wa.w,o8[3]);
    o8[4]=fmaf(s,wb.x,o8[4]); o8[5]=fmaf(s,wb.y,o8[5]);
    o8[6]=fmaf(s,wb.z,o8[6]); o8[7]=fmaf(s,wb.w,o8[7]);
  }
  #pragma unroll
  for(int m=16;m<64;m<<=1){
    ssum += __shfl_xor(ssum,m,64);
    #pragma unroll
    for(int j=0;j<8;j++) o8[j] += __shfl_xor(o8[j],m,64);
  }
  if(eg==0){
    float inv = (hi>lo)? 1.f/ssum : 0.f;
    float4 v0 = make_float4(o8[0]*inv, o8[1]*inv, o8[2]*inv, o8[3]*inv);
    float4 v1 = make_float4(o8[4]*inv, o8[5]*inv, o8[6]*inv, o8[7]*inv);
    *(float4*)&att[(size_t)n*128 + c8]     = v0;
    *(float4*)&att[(size_t)n*128 + c8 + 4] = v1;
  }
}

// ---------------- beta-gate + residual + softplus + LN (fp32; hn2 -> qs q-region) ----------------
__global__ void combine_ln(const float* __restrict__ att, float* __restrict__ qs,
                           const float* __restrict__ hn, const float* __restrict__ Wb,
                           const float* __restrict__ g, const float* __restrict__ b,
                           int N){
  int n = blockIdx.x*4 + (threadIdx.x>>6);
  if(n>=N) return;
  int lane = threadIdx.x&63;
  int c = 2*lane;
  float2 o  = *(const float2*)&att[(size_t)n*HID+c];
  float2 xr = *(const float2*)&qs[(size_t)n*256 + 128 + c];
  float bl = o.x*Wb[c] + o.y*Wb[c+1]
           + xr.x*Wb[HID+c] + xr.y*Wb[HID+c+1]
           + (o.x-xr.x)*Wb[2*HID+c] + (o.y-xr.y)*Wb[2*HID+c+1];
  bl = wsum64(bl);
  float beta = sigm_(bl);
  float u0 = beta*xr.x + (1.f-beta)*o.x;
  float u1 = beta*xr.y + (1.f-beta)*o.y;
  float2 hnv = *(const float2*)&hn[(size_t)n*HID+c];
  float h0 = hnv.x + sp_(u0);
  float h1 = hnv.y + sp_(u1);
  float s1 = wsum64(h0+h1);
  float s2 = wsum64(h0*h0+h1*h1);
  float mu = s1*(1.f/HID);
  float var = s2*(1.f/HID)-mu*mu;
  float rs = rsqrtf(var+1e-5f);
  float2 outv;
  outv.x = (h0-mu)*rs*g[c]+b[c];
  outv.y = (h1-mu)*rs*g[c+1]+b[c+1];
  *(float2*)&qs[(size_t)n*256 + c] = outv;   // hn2 into qs's dead q-region
}

// ---------------- fused FFN: triple-split, W direct from L2, fp32 LDS inter ----------------
__global__ __launch_bounds__(256) void ffn_fused(
    const float* __restrict__ hn2,
    const __hip_bfloat16* __restrict__ Wfhi, const __hip_bfloat16* __restrict__ Wfmi,
    const __hip_bfloat16* __restrict__ Wflo,
    const float* __restrict__ b1, const float* __restrict__ b2,
    const float* __restrict__ b3, const float* __restrict__ lng,
    const float* __restrict__ lnb, float* __restrict__ hout,
    float* __restrict__ hnout, int N){
  __shared__ float inter[2][64][IPADF];
  int row0 = blockIdx.x*64;
  int tid = threadIdx.x, lane = tid&63, wv = tid>>6;
  int ql = lane>>4, il = lane&15;

  auto loadbias = [&](const float* bp, float* bl8){
    float4 x0 = *(const float4*)&bp[il*8];
    float4 x1 = *(const float4*)&bp[il*8+4];
    bl8[0]=x0.x; bl8[1]=x0.y; bl8[2]=x0.z; bl8[3]=x0.w;
    bl8[4]=x1.x; bl8[5]=x1.y; bl8[6]=x1.z; bl8[7]=x1.w;
  };
  auto gemm_stage = [&](const __hip_bfloat16* Wh, const __hip_bfloat16* Wm,
                        const __hip_bfloat16* Wl,
                        bf16x8* ah, bf16x8* am, bf16x8* al, f32x4* acc){
    #pragma unroll
    for(int nj=0;nj<8;nj++) acc[nj] = (f32x4){0.f,0.f,0.f,0.f};
    #pragma unroll
    for(int kc=0;kc<4;kc++)
      #pragma unroll
      for(int nj=0;nj<8;nj++){
        size_t bo = (size_t)((kc*8+nj)*64 + lane)*8;
        bf16x8 bh = *(const bf16x8*)&Wh[bo];
        bf16x8 bm = *(const bf16x8*)&Wm[bo];
        bf16x8 bl = *(const bf16x8*)&Wl[bo];
        MFMA6(acc[nj], ah[kc], am[kc], al[kc], bh, bm, bl)
      }
  };

  f32x4 acc[8];
  bf16x8 ah[4], am[4], al[4];
  // ---- FFN1 (A from global, stride 256: hn2 lives in qs q-region) ----
  {
    int r = row0 + wv*16 + il;
    r = (r<N)? r : (N-1);
    const float* ap = hn2 + (size_t)r*256 + ql*8;
    #pragma unroll
    for(int kc=0;kc<4;kc++){
      float a8[8];
      float4 a0 = *(const float4*)(ap + kc*32);
      float4 a1 = *(const float4*)(ap + kc*32 + 4);
      a8[0]=a0.x;a8[1]=a0.y;a8[2]=a0.z;a8[3]=a0.w;
      a8[4]=a1.x;a8[5]=a1.y;a8[6]=a1.z;a8[7]=a1.w;
      split3_8(a8, ah[kc], am[kc], al[kc]);
    }
  }
  gemm_stage(Wfhi, Wfmi, Wflo, ah, am, al, acc);
  {
    float bl8[8]; loadbias(b1, bl8);
    #pragma unroll
    for(int r=0;r<4;r++){
      int lr = wv*16 + ql*4 + r;
      float o8[8];
      #pragma unroll
      for(int nj=0;nj<8;nj++) o8[nj] = sp_(acc[nj][r] + bl8[nj]);
      *(float4*)&inter[0][lr][il*8]   = make_float4(o8[0],o8[1],o8[2],o8[3]);
      *(float4*)&inter[0][lr][il*8+4] = make_float4(o8[4],o8[5],o8[6],o8[7]);
    }
  }
  __syncthreads();
  // ---- FFN2 (A from inter[0]) ----
  #pragma unroll
  for(int kc=0;kc<4;kc++){
    float a8[8];
    float4 a0 = *(float4*)&inter[0][wv*16+il][ql*8 + kc*32];
    float4 a1 = *(float4*)&inter[0][wv*16+il][ql*8 + kc*32 + 4];
    a8[0]=a0.x;a8[1]=a0.y;a8[2]=a0.z;a8[3]=a0.w;
    a8[4]=a1.x;a8[5]=a1.y;a8[6]=a1.z;a8[7]=a1.w;
    split3_8(a8, ah[kc], am[kc], al[kc]);
  }
  gemm_stage(Wfhi + 16384, Wfmi + 16384, Wflo + 16384, ah, am, al, acc);
  {
    float bl8[8]; loadbias(b2, bl8);
    #pragma unroll
    for(int r=0;r<4;r++){
      int lr = wv*16 + ql*4 + r;
      float o8[8];
      #pragma unroll
      for(int nj=0;nj<8;nj++) o8[nj] = sp_(acc[nj][r] + bl8[nj]);
      *(float4*)&inter[1][lr][il*8]   = make_float4(o8[0],o8[1],o8[2],o8[3]);
      *(float4*)&inter[1][lr][il*8+4] = make_float4(o8[4],o8[5],o8[6],o8[7]);
    }
  }
  __syncthreads();
  // ---- FFN3 (A from inter[1]) + epilogue ----
  #pragma unroll
  for(int kc=0;kc<4;kc++){
    float a8[8];
    float4 a0 = *(float4*)&inter[1][wv*16+il][ql*8 + kc*32];
    float4 a1 = *(float4*)&inter[1][wv*16+il][ql*8 + kc*32 + 4];
    a8[0]=a0.x;a8[1]=a0.y;a8[2]=a0.z;a8[3]=a0.w;
    a8[4]=a1.x;a8[5]=a1.y;a8[6]=a1.z;a8[7]=a1.w;
    split3_8(a8, ah[kc], am[kc], al[kc]);
  }
  gemm_stage(Wfhi + 2*16384, Wfmi + 2*16384, Wflo + 2*16384, ah, am, al, acc);
  {
    float bl8[8]; loadbias(b3, bl8);
    float lg8[8], lb8[8];
    loadbias(lng, lg8); loadbias(lnb, lb8);
    #pragma unroll
    for(int r=0;r<4;r++){
      int rr = row0 + wv*16 + ql*4 + r;
      if(rr >= N) continue;     // uniform across il -> shfl-safe
      float rv8[8];
      {
        const float* rp = hn2 + (size_t)rr*256 + il*8;
        float4 r0 = *(const float4*)rp;
        float4 r1 = *(const float4*)(rp+4);
        rv8[0]=r0.x;rv8[1]=r0.y;rv8[2]=r0.z;rv8[3]=r0.w;
        rv8[4]=r1.x;rv8[5]=r1.y;rv8[6]=r1.z;rv8[7]=r1.w;
      }
      float t8[8], s1=0.f, s2=0.f;
      #pragma unroll
      for(int nj=0;nj<8;nj++){
        float x = sp_(acc[nj][r] + bl8[nj]) + rv8[nj];
        t8[nj]=x; s1+=x; s2+=x*x;
      }
      s1 = wsum16(s1); s2 = wsum16(s2);
      float mu = s1*(1.f/128.f);
      float var = s2*(1.f/128.f) - mu*mu;
      float rsg = rsqrtf(var + 1e-5f);
      *(float4*)&hout[(size_t)rr*128 + il*8]     = make_float4(t8[0],t8[1],t8[2],t8[3]);
      *(float4*)&hout[(size_t)rr*128 + il*8 + 4] = make_float4(t8[4],t8[5],t8[6],t8[7]);
      float o8[8];
      #pragma unroll
      for(int nj=0;nj<8;nj++) o8[nj] = (t8[nj]-mu)*rsg*lg8[nj] + lb8[nj];
      *(float4*)&hnout[(size_t)rr*128 + il*8]     = make_float4(o8[0],o8[1],o8[2],o8[3]);
      *(float4*)&hnout[(size_t)rr*128 + il*8 + 4] = make_float4(o8[4],o8[5],o8[6],o8[7]);
    }
  }
}

// ---------------- pooling + output head (block per graph) ----------------
__global__ void pool_head(const float* __restrict__ h, const int* __restrict__ batch,
                          const float* __restrict__ Wo1, const float* __restrict__ bo1,
                          const float* __restrict__ Wo2, const float* __restrict__ bo2,
                          float* __restrict__ out, int N){
  int gid = blockIdx.x;
  int t = threadIdx.x;  // 128 threads
  int lo = lb_(batch, N, gid), hi = lb_(batch, N, gid+1);
  __shared__ float pl[128];
  __shared__ float red[128];
  float s = 0.f;
  for(int i=lo;i<hi;i++) s += h[(size_t)i*HID + t];
  pl[t] = s;
  __syncthreads();
  float acc = bo1[t];
  for(int c=0;c<128;c++) acc = fmaf(pl[c], Wo1[c*HID+t], acc);
  red[t] = sp_(acc)*Wo2[t];
  __syncthreads();
  for(int off=64;off>0;off>>=1){
    if(t<off) red[t]+=red[t+off];
    __syncthreads();
  }
  if(t==0) out[gid] = red[0] + bo2[0];
}

extern "C" void kernel_launch(void* const* d_in, const int* in_sizes, int n_in,
                              void* d_out, int out_size, void* d_ws, size_t ws_size,
                              hipStream_t stream){
  const float* h_in = (const float*)d_in[0];
  const float* pos  = (const float*)d_in[1];
  const float* ew   = (const float*)d_in[2];
  const float* Wq = (const float*)d_in[3];  const float* bq = (const float*)d_in[4];
  const float* Wk = (const float*)d_in[5];  const float* bk = (const float*)d_in[6];
  const float* Wv = (const float*)d_in[7];  const float* bv = (const float*)d_in[8];
  const float* We = (const float*)d_in[9];
  const float* Wsk= (const float*)d_in[10]; const float* bsk=(const float*)d_in[11];
  const float* Wbeta=(const float*)d_in[12];
  const float* W1=(const float*)d_in[13]; const float* b1=(const float*)d_in[14];
  const float* W2=(const float*)d_in[15]; const float* b2=(const float*)d_in[16];
  const float* W3=(const float*)d_in[17]; const float* b3=(const float*)d_in[18];
  const float* lng=(const float*)d_in[19]; const float* lnb=(const float*)d_in[20];
  const float* Wo1=(const float*)d_in[21]; const float* bo1=(const float*)d_in[22];
  const float* Wo2=(const float*)d_in[23]; const float* bo2=(const float*)d_in[24];
  const int* ei    = (const int*)d_in[25];
  const int* batch = (const int*)d_in[26];
  int N = in_sizes[0]/HID;
  int E = in_sizes[2];
  int G = out_size;
  float* out = (float*)d_out;

  char* ws = (char*)d_ws;
  size_t off=0;
  auto alloc=[&](size_t bytes)->char*{
    char* p = ws + off;
    off = (off + bytes + 255) & ~(size_t)255;
    return p;
  };
  float* efs   =(float*)alloc((size_t)E*12*4);
  int* esrc    =(int*)  alloc((size_t)E*4);
  int* csr     =(int*)  alloc((size_t)E*4);
  int* counts  =(int*)  alloc((size_t)N*4);
  int* counts2 =(int*)  alloc((size_t)N*4);
  int* rowst   =(int*)  alloc((size_t)(N+1)*4);
  int* tmp     =(int*)  alloc((size_t)N*4);
  int* bsums   =(int*)  alloc(256*4);
  int* boffs   =(int*)  alloc(256*4);
  float* hnf   =(float*)alloc((size_t)N*HID*4);      // LN(h) fp32
  float* qsb   =(float*)alloc((size_t)N*256*4);      // q | skip (q-region reused as hn2)
  float* kvb   =(float*)alloc((size_t)N*256*4);      // k | v
  float* qwb   =(float*)alloc((size_t)N*48*4);
  float* att   =(float*)alloc((size_t)N*HID*4);
  float* hcur  =(float*)alloc((size_t)N*HID*4);
  __hip_bfloat16* Wqkvs_t =(__hip_bfloat16*)alloc((size_t)3*NLAYER*5*16384*2);  // hi|mid|lo
  __hip_bfloat16* Wffn_t  =(__hip_bfloat16*)alloc((size_t)3*NLAYER*3*16384*2);  // hi|mid|lo
  float* bqkvs =(float*)alloc((size_t)NLAYER*640*4);
  size_t ws_used = off;

  const int QT = NLAYER*5*16384;
  const int FT = NLAYER*3*16384;
  int ebl = (E+255)/256;
  int nb  = (N+255)/256;
  int nwb = (N+3)/4;
  int nrb128 = (N+127)/128;
  int nrb64  = (N+63)/64;
  dim3 gqkvs(5, nrb128);

  // Normalize workspace state inside the captured graph (consistent launches).
  hipMemsetAsync(ws, 0, (ws_used <= ws_size ? ws_used : ws_size), stream);

  count_dst<<<ebl,256,0,stream>>>(ei,counts,E);
  scan1<<<nb,256,0,stream>>>(counts,tmp,bsums,N);
  scan2<<<1,256,0,stream>>>(bsums,boffs,nb);
  finalize_rs<<<nb,256,0,stream>>>(tmp,boffs,rowst,N);
  csr_scatter<<<ebl,256,0,stream>>>(ei,rowst,counts2,csr,E);
  sort_seg<<<nb,256,0,stream>>>(rowst,csr,N);          // deterministic order
  edge_feat<<<ebl,256,0,stream>>>(pos,ew,ei,csr,efs,esrc,E);
  {
    int tot = QT + FT + NLAYER*640;
    pack_w<<<(tot+255)/256,256,0,stream>>>(Wq,Wk,Wv,Wsk,bq,bk,bv,bsk,We,W1,W2,W3,
                                           Wqkvs_t,bqkvs,Wffn_t);
  }

  ln_node<<<nwb,256,0,stream>>>(h_in,lng,lnb,hnf,N);
  for(int l=0;l<NLAYER;l++){
    const float* We_l = We + (size_t)l*(KRBF+1)*HID;
    const float* Wb_l = Wbeta + (size_t)l*3*HID;
    const float* b1_l = b1 + (size_t)l*HID;
    const float* b2_l = b2 + (size_t)l*HID;
    const float* b3_l = b3 + (size_t)l*HID;
    const __hip_bfloat16* Wq_hi = Wqkvs_t + (size_t)l*5*16384;
    const __hip_bfloat16* Wq_mi = Wqkvs_t + QT + (size_t)l*5*16384;
    const __hip_bfloat16* Wq_lo = Wqkvs_t + 2*(size_t)QT + (size_t)l*5*16384;
    const __hip_bfloat16* Wf_hi = Wffn_t + (size_t)l*3*16384;
    const __hip_bfloat16* Wf_mi = Wffn_t + FT + (size_t)l*3*16384;
    const __hip_bfloat16* Wf_lo = Wffn_t + 2*(size_t)FT + (size_t)l*3*16384;

    gemm_qkvs<<<gqkvs,256,0,stream>>>(hnf, Wq_hi, Wq_mi, Wq_lo, bqkvs + l*640,
                                      qsb, kvb, qwb, N);
    attn_fused7<<<nwb,256,0,stream>>>(qsb,kvb,qwb,efs,esrc,We_l,rowst,att,N);
    combine_ln<<<nwb,256,0,stream>>>(att,qsb,hnf,Wb_l,lng,lnb,N);
    ffn_fused<<<nrb64,256,0,stream>>>(qsb, Wf_hi, Wf_mi, Wf_lo,
                                      b1_l,b2_l,b3_l,lng,lnb,hcur,hnf,N);
  }
  pool_head<<<G,128,0,stream>>>(hcur,batch,Wo1,bo1,Wo2,bo2,out,N);
}